// Round 8
// baseline (83.832 us; speedup 1.0000x reference)
//
#include <hip/hip_runtime.h>
#include <math.h>

// DotDetectionLoss on MI355X — ONE kernel node (64 blocks), strip binning,
// end-of-kernel value-flag reduction (R4-validated spin; no cooperative launch,
// no start-of-block spin — R5 lesson).
// pred: (16, 4096, 4) f32 = [cls, x, y, conf]; gt: (16, 1024, 3) f32 = [cls, x, y]
// out: float[2] = {obj_loss, reg_loss}
//
// Math: sigmoid(2.5-d) monotone in d => masked argmax(score) == argmin(d^2) among
// {class match, d2 <= 6.25}; score>=0.5 <=> d2 <= 6.25 (+1e-12 is sub-ulp).
// Spatial hash, strip variant: block (b,q) bins only preds in y-cell-rows
// [16q-1, 16q+16] (18 rows x 64 cols of 8px cells) and matches targets with
// floor(ty/128)==q. Guard rows make the candidate superset complete for r=2.5
// (+0.01 window guard); exact d2<=6.25 decides. Tie-break
// (d2<bd)||(d2==bd&&p<bp) == JAX argmax first-index.
// Obj split: bce(x,1)=bce(x,0)-x => obj = [sum_p bce0(x_p) - sum_correct x_p]/BP.
// Cross-block dedupe without pre-zeroing: atomicExch(wflags[p], MAGIC); poison
// 0xAAAAAAAA != MAGIC (validated R7). Final: per-block partials + ready=MAGIC
// release; block 0 spins (validated R4; 64 blocks trivially co-resident).

#define NB 16
#define NP 4096
#define NT 1024
#define MAGIC 0x5CA1AB1Eu
#define NROW 18
#define NC (NROW * 64)      // 1152 strip cells
#define BCAP 2048           // sbins capacity (strip avg ~1152, sigma ~29)

// ws layout (bytes): wflags u32[NB*NP] (256 KB) | partials f32[128] | ready u32[64]
#define O_WFLAGS 0
#define O_PART   (NB * NP * 4)
#define O_READY  (O_PART + 128 * 4)

__global__ __launch_bounds__(1024) void k_all(
    const float4* __restrict__ pred, const float* __restrict__ gt,
    unsigned* __restrict__ wflags, float* __restrict__ partials,
    unsigned* __restrict__ ready, float* __restrict__ out)
{
    const int bid = blockIdx.x;
    const int b = bid >> 2, q = bid & 3;      // image, strip/quarter
    const int tid = threadIdx.x, lane = tid & 63, wave = tid >> 6;

    __shared__ unsigned short scnt[NC];       // counts -> starts -> ENDs
    __shared__ unsigned short sbins[BCAP];    // strip pred ids grouped by cell
    __shared__ float2 sxy[NT];                // gt xy
    __shared__ unsigned short slist[256];     // owned correct preds
    __shared__ unsigned scount;
    __shared__ unsigned wsum[9];
    __shared__ float pc[2];                   // obj partial, score partial

    const float4* pb = pred + (size_t)b * NP;
    const float*  gb = gt + (size_t)b * NT * 3;
    const int rbase = 16 * q - 1;             // first cell row of this strip

    // ---- init LDS ----
    if (tid < NC / 2) ((unsigned*)scnt)[tid] = 0u;
    if (tid == 0) scount = 0u;
    if (tid < 2) pc[tid] = 0.0f;
    sxy[tid] = make_float2(gb[3 * tid + 1], gb[3 * tid + 2]);
    __syncthreads();

    // ---- count strip preds (packed u16 LDS atomics) + BCE baseline on quarter q ----
    int cellc[4];
    float lb = 0.0f;
    #pragma unroll
    for (int k = 0; k < 4; k++) {
        float4 pr = pb[tid + 1024 * k];
        int lr = (int)(pr.z * 0.125f) - rbase;
        int cell = (lr >= 0 && lr < NROW) ? lr * 64 + (int)(pr.y * 0.125f) : -1;
        cellc[k] = cell;
        if (cell >= 0)
            atomicAdd((unsigned*)scnt + (cell >> 1), (cell & 1) ? 0x10000u : 1u);
        if (k == q) {
            float x = pr.w;
            lb = fmaxf(x, 0.0f) + log1pf(expf(-fabsf(x)));   // bce(x, y=0)
        }
    }
    for (int off = 32; off; off >>= 1) lb += __shfl_down(lb, off, 64);
    if (lane == 0) atomicAdd(&pc[0], lb);
    __syncthreads();

    // ---- exclusive scan over 1152 cells (2 cells/thread, waves 0..8 full) ----
    const bool act = tid < NC / 2;
    unsigned sc0 = 0, ssum = 0, v = 0;
    if (act) {
        sc0 = scnt[tid * 2];
        ssum = sc0 + (unsigned)scnt[tid * 2 + 1];
        v = ssum;
        for (int off = 1; off < 64; off <<= 1) {
            unsigned o = __shfl_up(v, off, 64);
            if (lane >= off) v += o;
        }
        if (lane == 63) wsum[wave] = v;
    }
    __syncthreads();
    if (act) {
        unsigned wbase = 0;
        for (int w = 0; w < wave; w++) wbase += wsum[w];
        unsigned tbase = wbase + v - ssum;
        scnt[tid * 2]     = (unsigned short)tbase;        // exclusive start
        scnt[tid * 2 + 1] = (unsigned short)(tbase + sc0);
    }
    __syncthreads();

    // ---- fill (cursor = packed atomic; post-fill scnt[c] == END of cell c) ----
    #pragma unroll
    for (int k = 0; k < 4; k++) {
        int cell = cellc[k];
        if (cell >= 0) {
            unsigned old = atomicAdd((unsigned*)scnt + (cell >> 1),
                                     (cell & 1) ? 0x10000u : 1u);
            unsigned pos = (cell & 1) ? (old >> 16) : (old & 0xFFFFu);
            if (pos < BCAP) sbins[pos] = (unsigned short)(tid + 1024 * k);
        }
    }
    __syncthreads();

    // ---- match: one target per thread, only targets in this strip ----
    {
        const int t = tid;
        float2 txy = sxy[t];
        float tx = txy.x, ty = txy.y;
        if ((int)(ty * 0.0078125f) == q) {               // floor(ty/128) == q
            float tcl = gb[3 * t];
            int x0 = (int)floorf((tx - 2.51f) * 0.125f); if (x0 < 0) x0 = 0;
            int x1 = (int)((tx + 2.51f) * 0.125f);       if (x1 > 63) x1 = 63;
            int y0 = (int)floorf((ty - 2.51f) * 0.125f); if (y0 < 0) y0 = 0;
            int y1 = (int)((ty + 2.51f) * 0.125f);       if (y1 > 63) y1 = 63;
            int l0 = y0 - rbase, l1 = y1 - rbase;        // in [0,17] by construction
            float bd = 3.0e38f; int bp = 0x7fffffff;
            for (int lr = l0; lr <= l1; lr++)
                for (int cx = x0; cx <= x1; cx++) {
                    int c = lr * 64 + cx;
                    unsigned s0 = c ? (unsigned)scnt[c - 1] : 0u;
                    unsigned s1 = (unsigned)scnt[c];
                    for (unsigned kk = s0; kk < s1; kk++) {
                        int p = sbins[kk];
                        float4 pr = pb[p];
                        if (pr.x == tcl) {
                            float dx = pr.y - tx, dy = pr.z - ty;
                            float d2 = fmaf(dy, dy, dx * dx);
                            if (d2 < bd || (d2 == bd && p < bp)) { bd = d2; bp = p; }
                        }
                    }
                }
            if (bd <= 6.25f) {
                unsigned old = atomicExch(&wflags[b * NP + bp], MAGIC);
                if (old != MAGIC) {
                    unsigned w = atomicAdd(&scount, 1u);
                    if (w < 256u) slist[w] = (unsigned short)bp;
                }
            }
        }
    }
    __syncthreads();

    // ---- reg + obj correction: one wave per owned correct pred (16 waves) ----
    {
        unsigned n = scount; if (n > 256u) n = 256u;
        float lc = 0.0f, ls = 0.0f;
        for (unsigned e = (unsigned)wave; e < n; e += 16) {
            int p = slist[e];
            float4 pr = pb[p];
            float md = 1.0e30f;
            #pragma unroll 4
            for (int t = lane; t < NT; t += 64) {
                float2 xy = sxy[t];
                float dx = pr.y - xy.x, dy = pr.z - xy.y;
                md = fminf(md, fmaf(dy, dy, dx * dx));
            }
            for (int off = 32; off; off >>= 1)
                md = fminf(md, __shfl_down(md, off, 64));
            if (lane == 0) {
                float dd = sqrtf(md + 1e-12f);
                ls += 1.0f / (1.0f + expf(dd - 2.5f));
                lc += pr.w;                   // bce(x,1) = bce(x,0) - x
            }
        }
        if (lane == 0 && (lc != 0.0f || ls != 0.0f)) {
            atomicAdd(&pc[0], -lc);           // obj partial -= correction
            atomicAdd(&pc[1], ls);
        }
    }
    __syncthreads();

    // ---- publish partials + ready flag; block 0 reduces (R4-validated spin) ----
    if (tid == 0) {
        __hip_atomic_store(&partials[bid], pc[0], __ATOMIC_RELAXED,
                           __HIP_MEMORY_SCOPE_AGENT);
        __hip_atomic_store(&partials[64 + bid], pc[1], __ATOMIC_RELAXED,
                           __HIP_MEMORY_SCOPE_AGENT);
        __threadfence();
        __hip_atomic_store(&ready[bid], MAGIC, __ATOMIC_RELEASE,
                           __HIP_MEMORY_SCOPE_AGENT);
        if (bid == 0) {
            // 64 blocks (16 waves, ~16 KB LDS) on 256 CUs: all co-resident
            float a0 = pc[0], a1 = pc[1];
            for (int i = 1; i < 64; i++) {
                while (__hip_atomic_load(&ready[i], __ATOMIC_ACQUIRE,
                                         __HIP_MEMORY_SCOPE_AGENT) != MAGIC)
                    __builtin_amdgcn_s_sleep(1);
                a0 += __hip_atomic_load(&partials[i], __ATOMIC_RELAXED,
                                        __HIP_MEMORY_SCOPE_AGENT);
                a1 += __hip_atomic_load(&partials[64 + i], __ATOMIC_RELAXED,
                                        __HIP_MEMORY_SCOPE_AGENT);
            }
            const float inv = 1.0f / (float)(NB * NP);
            out[0] = a0 * inv;                // obj_loss
            out[1] = 1.0f - a1 * inv;         // reg_loss
        }
    }
}

extern "C" void kernel_launch(void* const* d_in, const int* in_sizes, int n_in,
                              void* d_out, int out_size, void* d_ws, size_t ws_size,
                              hipStream_t stream) {
    const float4* pred = (const float4*)d_in[0];
    const float*  gt   = (const float*)d_in[1];
    char* w = (char*)d_ws;
    unsigned* wflags   = (unsigned*)(w + O_WFLAGS);
    float*    partials = (float*)(w + O_PART);
    unsigned* ready    = (unsigned*)(w + O_READY);

    k_all<<<4 * NB, 1024, 0, stream>>>(pred, gt, wflags, partials, ready,
                                       (float*)d_out);
}

// Round 9
// 73.333 us; speedup vs baseline: 1.1432x; 1.1432x over previous
//
#include <hip/hip_runtime.h>
#include <math.h>

// DotDetectionLoss on MI355X — ONE kernel node: R7's k_all (64 blocks, per-block
// full-image binning — the validated 73µs config) + R6-validated TICKET finalize
// (no spin anywhere; R8's block-0 poll loop regressed and is reverted).
// pred: (16, 4096, 4) f32 = [cls, x, y, conf]; gt: (16, 1024, 3) f32 = [cls, x, y]
// out: float[2] = {obj_loss, reg_loss}
//
// Math: sigmoid(2.5-d) monotone in d => masked argmax(score) == argmin(d^2) among
// {class match, d2 <= 6.25}; score>=0.5 <=> d2 <= 6.25 (+1e-12 is sub-ulp).
// Spatial hash 64x64 cells (8px): r=2.5 disc spans <=2x2 cells (+0.01 window
// guard; superset safe — exact d2<=6.25 decides). Tie-break
// (d2<bd)||(d2==bd&&p<bp) == JAX argmax first-index (order-independent).
// Obj split: bce(x,1)=bce(x,0)-x => obj = [sum_p bce0(x_p) - sum_correct x_p]/BP.
// Poison-based idioms (harness re-poisons ws to 0xAA before EVERY launch):
//   dedupe:  atomicExch(wflags[p], MAGIC), first setter sees != MAGIC (R7-valid)
//   ticket:  starts 0xAAAAAAAA; 64th incrementer sees old == 0xAAAAAAAA+63.

#define NB 16
#define NP 4096
#define NT 1024
#define MAGIC 0x5CA1AB1Eu
#define TICKET0 0xAAAAAAAAu

// ws layout (bytes): wflags u32[NB*NP] (256 KB) | partials f32[128] | ticket u32
#define O_WFLAGS 0
#define O_PART   (NB * NP * 4)
#define O_TICKET (O_PART + 128 * 4)

__global__ __launch_bounds__(1024) void k_all(
    const float4* __restrict__ pred, const float* __restrict__ gt,
    unsigned* __restrict__ wflags, float* __restrict__ partials,
    unsigned* __restrict__ ticket, float* __restrict__ out)
{
    const int bid = blockIdx.x;
    const int b = bid >> 2, q = bid & 3;      // 4 blocks per image
    const int tid = threadIdx.x, lane = tid & 63, wave = tid >> 6;

    __shared__ unsigned short scnt[4096];     // cell counts -> cursors -> ENDs
    __shared__ unsigned short sbins[4096];    // pred ids grouped by cell
    __shared__ float2 sxy[NT];                // gt xy
    __shared__ unsigned short slist[256];     // owned correct preds
    __shared__ unsigned scount;
    __shared__ unsigned wsum[16];
    __shared__ float pc[2];                   // obj partial, score partial
    __shared__ int slast;                     // "this block is the ticket-closer"

    const float4* pb = pred + (size_t)b * NP;
    const float*  gb = gt + (size_t)b * NT * 3;

    // ---- init LDS ----
    ((unsigned*)scnt)[tid] = 0u;
    ((unsigned*)scnt)[tid + 1024] = 0u;
    if (tid == 0) scount = 0u;
    if (tid < 2) pc[tid] = 0.0f;
    sxy[tid] = make_float2(gb[3 * tid + 1], gb[3 * tid + 2]);
    __syncthreads();

    // ---- count (packed u16 LDS atomics; halfwords <=4096, no carry) + BCE
    //      baseline on this block's owned quarter (k==q element, no extra load) ----
    int cellc[4];
    float lb = 0.0f;
    #pragma unroll
    for (int k = 0; k < 4; k++) {
        float4 pr = pb[tid + 1024 * k];
        int cell = (int)(pr.y * 0.125f) + ((int)(pr.z * 0.125f) << 6);
        cellc[k] = cell;
        atomicAdd((unsigned*)scnt + (cell >> 1), (cell & 1) ? 0x10000u : 1u);
        if (k == q) {
            float x = pr.w;
            lb = fmaxf(x, 0.0f) + log1pf(expf(-fabsf(x)));   // bce(x, y=0)
        }
    }
    for (int off = 32; off; off >>= 1) lb += __shfl_down(lb, off, 64);
    if (lane == 0) atomicAdd(&pc[0], lb);
    __syncthreads();

    // ---- exclusive scan over 4096 cells (4 cells/thread, 16 waves) ----
    {
        int base = tid * 4;
        unsigned loc[4], s = 0;
        #pragma unroll
        for (int i = 0; i < 4; i++) { loc[i] = s; s += (unsigned)scnt[base + i]; }
        unsigned v = s;
        for (int off = 1; off < 64; off <<= 1) {
            unsigned o = __shfl_up(v, off, 64);
            if (lane >= off) v += o;
        }
        if (lane == 63) wsum[wave] = v;
        __syncthreads();
        unsigned wbase = 0;
        for (int w = 0; w < wave; w++) wbase += wsum[w];
        unsigned tbase = wbase + v - s;
        #pragma unroll
        for (int i = 0; i < 4; i++) scnt[base + i] = (unsigned short)(tbase + loc[i]);
    }
    __syncthreads();

    // ---- fill (cursor = packed atomic; post-fill scnt[c] == END of cell c) ----
    #pragma unroll
    for (int k = 0; k < 4; k++) {
        int cell = cellc[k];
        unsigned old = atomicAdd((unsigned*)scnt + (cell >> 1), (cell & 1) ? 0x10000u : 1u);
        sbins[(cell & 1) ? (old >> 16) : (old & 0xFFFFu)] = (unsigned short)(tid + 1024 * k);
    }
    __syncthreads();

    // ---- match: waves 0-3, one target per thread (targets q*256 .. q*256+255) ----
    if (tid < 256) {
        const int t = q * 256 + tid;
        float tcl = gb[3 * t];
        float2 txy = sxy[t];
        float tx = txy.x, ty = txy.y;
        int x0 = (int)floorf((tx - 2.51f) * 0.125f); if (x0 < 0) x0 = 0;
        int x1 = (int)((tx + 2.51f) * 0.125f);       if (x1 > 63) x1 = 63;
        int y0 = (int)floorf((ty - 2.51f) * 0.125f); if (y0 < 0) y0 = 0;
        int y1 = (int)((ty + 2.51f) * 0.125f);       if (y1 > 63) y1 = 63;
        float bd = 3.0e38f; int bp = 0x7fffffff;
        for (int cy = y0; cy <= y1; cy++)
            for (int cx = x0; cx <= x1; cx++) {
                int c = cx + (cy << 6);
                unsigned s0 = c ? (unsigned)scnt[c - 1] : 0u;
                unsigned s1 = (unsigned)scnt[c];
                for (unsigned k = s0; k < s1; k++) {
                    int p = sbins[k];
                    float4 pr = pb[p];
                    if (pr.x == tcl) {
                        float dx = pr.y - tx, dy = pr.z - ty;
                        float d2 = fmaf(dy, dy, dx * dx);
                        if (d2 < bd || (d2 == bd && p < bp)) { bd = d2; bp = p; }
                    }
                }
            }
        if (bd <= 6.25f) {
            // cross-block dedupe: first exchanger owns (poison 0xAAAAAAAA != MAGIC)
            unsigned old = atomicExch(&wflags[b * NP + bp], MAGIC);
            if (old != MAGIC)
                slist[atomicAdd(&scount, 1u)] = (unsigned short)bp;
        }
    }
    __syncthreads();

    // ---- reg + obj correction: one wave per owned correct pred (16 waves) ----
    {
        unsigned n = scount;
        float lc = 0.0f, ls = 0.0f;
        for (unsigned e = (unsigned)wave; e < n; e += 16) {
            int p = slist[e];
            float4 pr = pb[p];
            float md = 1.0e30f;
            #pragma unroll 4
            for (int t = lane; t < NT; t += 64) {
                float2 xy = sxy[t];
                float dx = pr.y - xy.x, dy = pr.z - xy.y;
                md = fminf(md, fmaf(dy, dy, dx * dx));
            }
            for (int off = 32; off; off >>= 1)
                md = fminf(md, __shfl_down(md, off, 64));
            if (lane == 0) {
                float dd = sqrtf(md + 1e-12f);
                ls += 1.0f / (1.0f + expf(dd - 2.5f));
                lc += pr.w;                   // bce(x,1) = bce(x,0) - x
            }
        }
        if (lane == 0 && (lc != 0.0f || ls != 0.0f)) {
            atomicAdd(&pc[0], -lc);           // obj partial -= correction
            atomicAdd(&pc[1], ls);
        }
    }
    __syncthreads();

    // ---- ticket finalize (R6-validated; no spin, no extra node) ----
    if (tid == 0) {
        partials[bid]      = pc[0];           // obj partial
        partials[64 + bid] = pc[1];           // score partial
        __threadfence();                      // order partials before ticket
        unsigned old = atomicAdd(ticket, 1u); // device-scope
        slast = (old == TICKET0 + 63u);       // 64th incrementer closes
    }
    __syncthreads();
    if (slast && tid < 128) {
        __threadfence();                      // all 63 other partials visible
        float v = partials[wave * 64 + lane];
        for (int off = 32; off; off >>= 1) v += __shfl_down(v, off, 64);
        if (lane == 0) {
            const float inv = 1.0f / (float)(NB * NP);
            if (wave == 0) out[0] = v * inv;            // obj_loss
            else           out[1] = 1.0f - v * inv;     // reg_loss
        }
    }
}

extern "C" void kernel_launch(void* const* d_in, const int* in_sizes, int n_in,
                              void* d_out, int out_size, void* d_ws, size_t ws_size,
                              hipStream_t stream) {
    const float4* pred = (const float4*)d_in[0];
    const float*  gt   = (const float*)d_in[1];
    char* w = (char*)d_ws;
    unsigned* wflags   = (unsigned*)(w + O_WFLAGS);
    float*    partials = (float*)(w + O_PART);
    unsigned* ticket   = (unsigned*)(w + O_TICKET);

    k_all<<<4 * NB, 1024, 0, stream>>>(pred, gt, wflags, partials, ticket,
                                       (float*)d_out);
}